// Round 11
// baseline (102.353 us; speedup 1.0000x reference)
//
#include <hip/hip_runtime.h>
#include <hip/hip_bf16.h>
#include <math.h>

#define EPS 1e-8f
#define BB 32
#define SS 64
#define HH 200
#define LL 20
#define KST 232   // f16 LDS row stride (464B -> 2-way bank walk)
#define S16ST 72  // S16 row stride (f16)
#define BHST 72   // BH row stride (f16)
#define MLST 208  // meanL row stride (f16)

typedef float f32x4 __attribute__((ext_vector_type(4)));
typedef _Float16 f16x8v __attribute__((ext_vector_type(8)));
typedef _Float16 f16x2 __attribute__((ext_vector_type(2)));

// ONE kernel, grid 512 x 512 (256 groups of 2: 1 merged type-A + 1 type-C).
// r11 = r10 with type-A quarters MERGED (2 sequential 16-row quarters per block):
// B staging / B-diag norms / BH build amortized 2x; grid 768->512 = exactly one
// residency round at 2 blocks/CU. Type C is r10-VERBATIM. XCD swizzle kept.
//
// Type A LDS (floats, 19088 = 76.35 KB -> 2 blocks/CU):
//   [0,1856)       AT16 16xKST f16 (re-staged per quarter)
//   [1856,9344)    BH 208xBHST f16 (rebuilt from BT16 for quarter 2)
//   [9344,9920)    S16 16xS16ST f16 (per quarter)
//   [9920,17344)   BT16 64xKST f16 — PERSISTENT across quarters
//   [17344,17360)  nrmA(16, per quarter)  [17360,17424) nrmB(64, persistent)
//   [17424,19088)  meanL 16xMLST f16 (per quarter)
//   phase-3 overlays: PB 48xKST [0,5568) | WB 32xKST [5568,9280) — cover AT16+BH
//   only; BT16/nrmB/meanL untouched. BH dead during phase 3, rebuilt next quarter.
// Type C LDS: r10 verbatim (17352 fl < 19088).
__global__ __launch_bounds__(512, 4) void fused_all_kernel(
        const float* __restrict__ conp, const float* __restrict__ conh,
        const float* __restrict__ w1, const float* __restrict__ w2,
        const float* __restrict__ w3, const float* __restrict__ w4,
        const float* __restrict__ w5, const float* __restrict__ w6,
        const float* __restrict__ w7, const float* __restrict__ w8,
        float* __restrict__ out) {
    __shared__ __align__(16) float smem[19088];
    int t = threadIdx.x;

    // XCD-aware swizzle (bijective on [0,512) = 8 x 64)
    int wg = ((blockIdx.x & 7) * 64) + (blockIdx.x >> 3);
    int grp = wg >> 1;
    int rem = wg & 1;

    int wv_ = __builtin_amdgcn_readfirstlane(t >> 6);
    int lane = t & 63;
    int q = lane >> 4, c = lane & 15;

    if (rem == 0) {
        // ================================ type A merged (2 x 16 self-rows)
        _Float16* AT16 = (_Float16*)smem;
        _Float16* BHh  = (_Float16*)(smem + 1856);
        _Float16* S16h = (_Float16*)(smem + 9344);
        _Float16* BT16 = (_Float16*)(smem + 9920);
        float* nrmA  = smem + 17344;
        float* nrmB  = smem + 17360;
        _Float16* meanLh = (_Float16*)(smem + 17424);
        _Float16* PB = (_Float16*)smem;            // phase 3: 48xKST
        _Float16* WB = (_Float16*)(smem + 5568);   // phase 3: 32xKST

        int qp = grp & 1;              // quarter-pair: quarters {2qp, 2qp+1}
        int sdb = grp >> 1;            // 0..127
        int b = sdb & 31, sd = sdb >> 5;
        int dir = sd & 1, side = sd >> 1;
        const float* selfb = side ? conh : conp;
        const float* oppb  = side ? conp : conh;
        int fidx = dir ? 0 : (SS - 1);
        const float* fvr = oppb + (b * SS + fidx) * (2 * HH) + dir * HH;

        int arow = t / 25, ack = t % 25;

        float yv0[8], wf0[8], wf1[8], wf2[8];   // loaded at qi==0, persist

        for (int qi = 0; qi < 2; ++qi) {
            int qh = qp * 2 + qi;
            float xr[8];

            // ---- stage 16 self rows (regs kept); qi==0: + fvr, BT16, pads
            if (t < 400) {
                const float* xp = selfb + (b * SS + qh * 16 + arow) * (2 * HH) + dir * HH + ack * 8;
                *(float4*)&xr[0] = *(const float4*)xp; *(float4*)&xr[4] = *(const float4*)(xp + 4);
                if (qi == 0) {
                    *(float4*)&yv0[0] = *(const float4*)(fvr + ack * 8);
                    *(float4*)&yv0[4] = *(const float4*)(fvr + ack * 8 + 4);
                }
                f16x8v r8;
#pragma unroll
                for (int i = 0; i < 8; ++i) r8[i] = (_Float16)xr[i];
                *(f16x8v*)&AT16[arow * KST + ack * 8] = r8;
            }
            {
                f16x8v z8 = (f16x8v)(_Float16)0.f;
                if (t < 48) {   // AT16 pads (destroyed by PB each quarter)
                    int row = t / 3, ckp = 25 + t % 3;
                    *(f16x8v*)&AT16[row * KST + ckp * 8] = z8;
                }
                if (qi == 0) {
                    if (t >= 48 && t < 240) { int e2 = t - 48; int row = e2 / 3, ckp = 25 + e2 % 3;
                        *(f16x8v*)&BT16[row * KST + ckp * 8] = z8;
                    } else if (t >= 240 && t < 312) { int e2 = t - 240; int row = 200 + e2 / 9, c8 = (e2 % 9) * 8;
                        *(f16x8v*)&BHh[row * BHST + c8] = z8;
                    }
                } else {
                    if (t >= 48 && t < 120) {   // re-zero BH pad rows (destroyed by WB)
                        int e2 = t - 48; int row = 200 + e2 / 9, c8 = (e2 % 9) * 8;
                        *(f16x8v*)&BHh[row * BHST + c8] = z8;
                    }
                }
            }
            if (qi == 0) {
                for (int e = t; e < 1600; e += 512) {
                    int rw = e / 25, ck = e % 25, k = ck * 8;
                    const float* xp = oppb + (b * SS + rw) * (2 * HH) + dir * HH + k;
                    float xv[8];
                    *(float4*)&xv[0] = *(const float4*)xp; *(float4*)&xv[4] = *(const float4*)(xp + 4);
                    f16x8v r8;
#pragma unroll
                    for (int i = 0; i < 8; ++i) r8[i] = (_Float16)xv[i];
                    *(f16x8v*)&BT16[rw * KST + k] = r8;
                }
            }
            __syncthreads();   // B1

            // ---- MFMA: waves 0-3 S-tiles; wave 4 A-diag (+B-diag q1); waves 5-7
            //      B-diag (q1) + BH build (q1) / BH rebuild (q2)
            f32x4 accS = (f32x4){0.f, 0.f, 0.f, 0.f};
            if (wv_ < 4) {
                int ct = wv_;
                for (int ks = 0; ks < 7; ++ks) {
                    int kb = ks * 32 + q * 8;
                    f16x8v af  = *(const f16x8v*)&AT16[c * KST + kb];
                    f16x8v bf_ = *(const f16x8v*)&BT16[(ct * 16 + c) * KST + kb];
                    accS = __builtin_amdgcn_mfma_f32_16x16x32_f16(af, bf_, accS, 0, 0, 0);
                }
            } else {
                int dt = wv_ - 4;
                if (qi == 0) {
                    f32x4 accB = (f32x4){0.f, 0.f, 0.f, 0.f};
                    for (int ks = 0; ks < 7; ++ks) {
                        int kb = ks * 32 + q * 8;
                        f16x8v bf_ = *(const f16x8v*)&BT16[(dt * 16 + c) * KST + kb];
                        accB = __builtin_amdgcn_mfma_f32_16x16x32_f16(bf_, bf_, accB, 0, 0, 0);
                    }
                    if ((c >> 2) == q) nrmB[dt * 16 + c] = accB[c & 3];
                }
                if (dt == 0) {   // A diagonal, every quarter
                    f32x4 accA = (f32x4){0.f, 0.f, 0.f, 0.f};
                    for (int ks = 0; ks < 7; ++ks) {
                        int kb = ks * 32 + q * 8;
                        f16x8v af = *(const f16x8v*)&AT16[c * KST + kb];
                        accA = __builtin_amdgcn_mfma_f32_16x16x32_f16(af, af, accA, 0, 0, 0);
                    }
                    if ((c >> 2) == q) nrmA[c] = accA[c & 3];
                } else {         // BH (re)build from persistent BT16
                    for (int ch = dt - 1; ch < 25; ch += 3) {
                        f16x8v v = *(const f16x8v*)&BT16[lane * KST + ch * 8];
#pragma unroll
                        for (int i = 0; i < 8; ++i) BHh[(ch * 8 + i) * BHST + lane] = v[i];
                    }
                }
            }
            __syncthreads();   // B2

            if (wv_ < 4) {
                int col = wv_ * 16 + c;
                float no = sqrtf(nrmB[col]);
#pragma unroll
                for (int r = 0; r < 4; ++r) {
                    int row = q * 4 + r;
                    float ns = sqrtf(nrmA[row]);
                    S16h[row * S16ST + col] = (_Float16)(accS[r] / fmaxf(ns * no, EPS));
                }
            }
            __syncthreads();   // B3

            if (qi == 0 && t < 500) {   // w rows prefetch (persist both quarters)
                int wl = t / 25, wck = t % 25;
                const float* wp0 = (dir ? w2 : w1) + wl * HH + wck * 8;
                const float* wp1 = (dir ? w6 : w5) + wl * HH + wck * 8;
                const float* wp2 = (dir ? w8 : w7) + wl * HH + wck * 8;
                *(float4*)&wf0[0] = *(const float4*)wp0; *(float4*)&wf0[4] = *(const float4*)(wp0 + 4);
                *(float4*)&wf1[0] = *(const float4*)wp1; *(float4*)&wf1[4] = *(const float4*)(wp1 + 4);
                *(float4*)&wf2[0] = *(const float4*)wp2; *(float4*)&wf2[4] = *(const float4*)(wp2 + 4);
            }

            // ---- phase 2: wave 7 mean GEMM; waves 0-6 packed-f16 max
            f16x2 mx0, mx1, mx2, mx3;
            {
                f16x2 ninf = {(_Float16)(-INFINITY), (_Float16)(-INFINITY)};
                mx0 = ninf; mx1 = ninf; mx2 = ninf; mx3 = ninf;
            }
            if (wv_ == 7) {
                for (int nt = 0; nt < 13; ++nt) {
                    f32x4 macc = (f32x4){0.f, 0.f, 0.f, 0.f};
#pragma unroll
                    for (int k2 = 0; k2 < 2; ++k2) {
                        int kb = k2 * 32 + q * 8;
                        f16x8v sa = *(const f16x8v*)&S16h[c * S16ST + kb];
                        f16x8v bh = *(const f16x8v*)&BHh[(nt * 16 + c) * BHST + kb];
                        macc = __builtin_amdgcn_mfma_f32_16x16x32_f16(sa, bh, macc, 0, 0, 0);
                    }
                    int h = nt * 16 + c;
                    if (h < 200) {
#pragma unroll
                        for (int r = 0; r < 4; ++r)
                            meanLh[(q * 4 + r) * MLST + h] = (_Float16)(macc[r] * 0.125f);
                    }
                }
            } else if (t < 400) {
                const _Float16* srow = &S16h[arow * S16ST];
                const _Float16* bcol = &BT16[ack * 8];
                for (int kg = 0; kg < 8; ++kg) {
                    f16x8v sr = *(const f16x8v*)&srow[kg * 8];
#pragma unroll
                    for (int kk = 0; kk < 8; ++kk) {
                        _Float16 sh = sr[kk];
                        f16x2 sv = {sh, sh};
                        f16x8v bv = *(const f16x8v*)&bcol[(kg * 8 + kk) * KST];
                        f16x2 p0 = sv * __builtin_shufflevector(bv, bv, 0, 1);
                        f16x2 p1 = sv * __builtin_shufflevector(bv, bv, 2, 3);
                        f16x2 p2 = sv * __builtin_shufflevector(bv, bv, 4, 5);
                        f16x2 p3 = sv * __builtin_shufflevector(bv, bv, 6, 7);
                        mx0 = __builtin_elementwise_max(mx0, p0);
                        mx1 = __builtin_elementwise_max(mx1, p1);
                        mx2 = __builtin_elementwise_max(mx2, p2);
                        mx3 = __builtin_elementwise_max(mx3, p3);
                    }
                }
            }
            __syncthreads();   // B4 — PB/WB overlays (AT16+BH) may begin

            // ---- phase 3: matches m=0,1,2
#pragma unroll
            for (int m = 0; m < 3; ++m) {
                if (t < 400) {
                    float yv[8];
                    if (m == 0) {
#pragma unroll
                        for (int i = 0; i < 8; ++i) yv[i] = yv0[i];
                    } else if (m == 1) {
                        f16x8v yl = *(const f16x8v*)&meanLh[arow * MLST + ack * 8];
#pragma unroll
                        for (int i = 0; i < 8; ++i) yv[i] = (float)yl[i];
                    } else {
                        yv[0] = (float)mx0[0]; yv[1] = (float)mx0[1];
                        yv[2] = (float)mx1[0]; yv[3] = (float)mx1[1];
                        yv[4] = (float)mx2[0]; yv[5] = (float)mx2[1];
                        yv[6] = (float)mx3[0]; yv[7] = (float)mx3[1];
                    }
                    f16x8v r1, r2;
#pragma unroll
                    for (int i = 0; i < 8; ++i) {
                        r1[i] = (_Float16)(xr[i] * yv[i]);
                        r2[i] = (_Float16)(yv[i] * yv[i]);
                    }
                    if (m == 0) {
                        f16x8v r0;
#pragma unroll
                        for (int i = 0; i < 8; ++i) r0[i] = (_Float16)(xr[i] * xr[i]);
                        *(f16x8v*)&PB[(0 * 16 + arow) * KST + ack * 8] = r0;
                    }
                    *(f16x8v*)&PB[(1 * 16 + arow) * KST + ack * 8] = r1;
                    *(f16x8v*)&PB[(2 * 16 + arow) * KST + ack * 8] = r2;
                }
                if (t < 500) {
                    int wl = t / 25, wck = t % 25;
                    f16x8v wr;
                    if (m == 0) {
#pragma unroll
                        for (int i = 0; i < 8; ++i) wr[i] = (_Float16)(wf0[i] * wf0[i]);
                    } else if (m == 1) {
#pragma unroll
                        for (int i = 0; i < 8; ++i) wr[i] = (_Float16)(wf1[i] * wf1[i]);
                    } else {
#pragma unroll
                        for (int i = 0; i < 8; ++i) wr[i] = (_Float16)(wf2[i] * wf2[i]);
                    }
                    *(f16x8v*)&WB[wl * KST + wck * 8] = wr;
                }
                if (m == 0) {   // per-quarter zeros (PB/WB regions rebuilt each quarter)
                    f16x8v z8 = (f16x8v)(_Float16)0.f;
                    for (int e = t; e < 540; e += 512) {
                        if (e < 144) { int row = e / 3, ckp = 25 + e % 3;
                            *(f16x8v*)&PB[row * KST + ckp * 8] = z8;
                        } else if (e < 480) { int e2 = e - 144; int row = 20 + e2 / 28, ckp = e2 % 28;
                            *(f16x8v*)&WB[row * KST + ckp * 8] = z8;
                        } else { int e2 = e - 480; int row = e2 / 3, ckp = 25 + e2 % 3;
                            *(f16x8v*)&WB[row * KST + ckp * 8] = z8;
                        }
                    }
                }
                __syncthreads();

                if (wv_ < 2) {
                    int ntile = wv_;
                    f32x4 accA = (f32x4){0.f, 0.f, 0.f, 0.f};
                    f32x4 accD = (f32x4){0.f, 0.f, 0.f, 0.f};
                    f32x4 accB = (f32x4){0.f, 0.f, 0.f, 0.f};
                    for (int ks = 0; ks < 7; ++ks) {
                        int kb = ks * 32 + q * 8;
                        f16x8v bfw = *(const f16x8v*)&WB[(ntile * 16 + c) * KST + kb];
                        f16x8v a0 = *(const f16x8v*)&PB[(0 * 16 + c) * KST + kb];
                        f16x8v a1 = *(const f16x8v*)&PB[(1 * 16 + c) * KST + kb];
                        f16x8v a2 = *(const f16x8v*)&PB[(2 * 16 + c) * KST + kb];
                        accA = __builtin_amdgcn_mfma_f32_16x16x32_f16(a0, bfw, accA, 0, 0, 0);
                        accD = __builtin_amdgcn_mfma_f32_16x16x32_f16(a1, bfw, accD, 0, 0, 0);
                        accB = __builtin_amdgcn_mfma_f32_16x16x32_f16(a2, bfw, accB, 0, 0, 0);
                    }
                    int l_ = ntile * 16 + c;
                    if (l_ < LL) {
                        int chunk = (m == 0) ? 0 : (m == 1) ? 40 : 60;
#pragma unroll
                        for (int r = 0; r < 4; ++r) {
                            int s = qh * 16 + q * 4 + r;
                            float cosv = accD[r] / fmaxf(sqrtf(accA[r] * accB[r]), EPS);
                            out[side * (BB * SS * 160) + (b * SS + s) * 160 + dir * 80 + chunk + l_] = cosv;
                        }
                    }
                }
                // barrier after every m except the very last of the last quarter;
                // the qi==0,m==2 barrier protects PB from quarter-2's AT16 staging
                if (!(qi == 1 && m == 2)) __syncthreads();
            }
        }
    } else {
        // ================================ type C: 5-l pairwise, f16, w^2-on-A (r10 VERBATIM)
        _Float16* ATr = (_Float16*)smem;             // 64xKST raw A (f16)
        _Float16* BTr = (_Float16*)(smem + 7424);    // 64xKST raw B (f16)
        _Float16* w2L = (_Float16*)(smem + 14848);   // 5xKST w^2 (f16)
        float* nA5  = smem + 15432;                  // 5x64
        float* nB5  = smem + 15752;                  // 5x64
        float* cmL5 = smem + 16072;                  // 5x256

        int cblk = grp;              // 0..255
        int lg = cblk & 3;
        int db = cblk >> 2;          // 0..63
        int b = db & 31, dir = db >> 5;
        int l0 = lg * 5;
        const float* wsrc = dir ? w4 : w3;
        const float* Ag = conp + dir * HH;
        const float* Bg = conh + dir * HH;

        for (int e = t; e < 3200; e += 512) {
            int half = (e >= 1600) ? 1 : 0;
            int e2 = e - half * 1600;
            int rw = e2 / 25, ck = e2 % 25, k = ck * 8;
            const float* xp = (half ? Bg : Ag) + (b * SS + rw) * (2 * HH) + k;
            float xv[8];
            *(float4*)&xv[0] = *(const float4*)xp; *(float4*)&xv[4] = *(const float4*)(xp + 4);
            f16x8v r8;
#pragma unroll
            for (int i = 0; i < 8; ++i) r8[i] = (_Float16)xv[i];
            _Float16* dst = half ? BTr : ATr;
            *(f16x8v*)&dst[rw * KST + k] = r8;
        }
        {
            f16x8v z8 = (f16x8v)(_Float16)0.f;
            if (t < 384) {
                int half = (t >= 192) ? 1 : 0;
                int e2 = t - half * 192;
                int row = e2 / 3, ckp = 25 + e2 % 3;
                _Float16* dst = half ? BTr : ATr;
                *(f16x8v*)&dst[row * KST + ckp * 8] = z8;
            } else if (t < 399) {
                int e2 = t - 384;
                int wl = e2 / 3, ckp = 25 + e2 % 3;
                *(f16x8v*)&w2L[wl * KST + ckp * 8] = z8;
            }
            if (t < 125) {
                int wl = t / 25, wck = t % 25;
                const float* wp = wsrc + (l0 + wl) * HH + wck * 8;
                float wvv[8];
                *(float4*)&wvv[0] = *(const float4*)wp; *(float4*)&wvv[4] = *(const float4*)(wp + 4);
                f16x8v r8;
#pragma unroll
                for (int i = 0; i < 8; ++i) r8[i] = (_Float16)(wvv[i] * wvv[i]);
                *(f16x8v*)&w2L[wl * KST + wck * 8] = r8;
            }
        }
        __syncthreads();   // B1

        int m0 = (wv_ & 3) * 16;

        f32x4 z4 = (f32x4){0.f, 0.f, 0.f, 0.f};
        f32x4 acc0[4] = {z4, z4, z4, z4};
        f32x4 acc1[4] = {z4, z4, z4, z4};
        f32x4 acc2[4] = {z4, z4, z4, z4};

        if (wv_ < 4) {
            for (int ks = 0; ks < 7; ++ks) {
                int kb = ks * 32 + q * 8;
                f16x8v ar  = *(const f16x8v*)&ATr[(m0 + c) * KST + kb];
                f16x8v ww0 = *(const f16x8v*)&w2L[0 * KST + kb];
                f16x8v ww1 = *(const f16x8v*)&w2L[1 * KST + kb];
                f16x8v ww2 = *(const f16x8v*)&w2L[2 * KST + kb];
                f16x8v af0 = ar * ww0, af1 = ar * ww1, af2 = ar * ww2;
#pragma unroll
                for (int ct = 0; ct < 4; ++ct) {
                    f16x8v br = *(const f16x8v*)&BTr[(ct * 16 + c) * KST + kb];
                    acc0[ct] = __builtin_amdgcn_mfma_f32_16x16x32_f16(af0, br, acc0[ct], 0, 0, 0);
                    acc1[ct] = __builtin_amdgcn_mfma_f32_16x16x32_f16(af1, br, acc1[ct], 0, 0, 0);
                    acc2[ct] = __builtin_amdgcn_mfma_f32_16x16x32_f16(af2, br, acc2[ct], 0, 0, 0);
                }
            }
        } else {
            int d0 = (wv_ - 4) * 16;
            f32x4 nacA[5] = {z4, z4, z4, z4, z4};
            f32x4 nacB[5] = {z4, z4, z4, z4, z4};
            for (int ks = 0; ks < 7; ++ks) {
                int kb = ks * 32 + q * 8;
                f16x8v ar = *(const f16x8v*)&ATr[(d0 + c) * KST + kb];
                f16x8v br = *(const f16x8v*)&BTr[(d0 + c) * KST + kb];
#pragma unroll
                for (int li = 0; li < 5; ++li) {
                    f16x8v wf = *(const f16x8v*)&w2L[li * KST + kb];
                    f16x8v afw = ar * wf;
                    f16x8v bfw = br * wf;
                    nacA[li] = __builtin_amdgcn_mfma_f32_16x16x32_f16(afw, ar, nacA[li], 0, 0, 0);
                    nacB[li] = __builtin_amdgcn_mfma_f32_16x16x32_f16(bfw, br, nacB[li], 0, 0, 0);
                }
            }
            if ((c >> 2) == q) {
#pragma unroll
                for (int li = 0; li < 5; ++li) {
                    nA5[li * 64 + d0 + c] = nacA[li][c & 3];
                    nB5[li * 64 + d0 + c] = nacB[li][c & 3];
                }
            }
        }
        __syncthreads();   // B2

#define C_EPI(LI, ACC) do { \
    float na_[4], nb_[4]; \
    _Pragma("unroll") for (int r_ = 0; r_ < 4; ++r_) na_[r_] = sqrtf(nA5[(LI) * 64 + m0 + q * 4 + r_]); \
    _Pragma("unroll") for (int ct_ = 0; ct_ < 4; ++ct_) nb_[ct_] = sqrtf(nB5[(LI) * 64 + ct_ * 16 + c]); \
    float rowm_[4] = {-INFINITY, -INFINITY, -INFINITY, -INFINITY}; \
    float colm_[4] = {-INFINITY, -INFINITY, -INFINITY, -INFINITY}; \
    _Pragma("unroll") for (int ct_ = 0; ct_ < 4; ++ct_) { \
        _Pragma("unroll") for (int r_ = 0; r_ < 4; ++r_) { \
            float cv_ = (ACC)[ct_][r_] / fmaxf(na_[r_] * nb_[ct_], EPS); \
            rowm_[r_] = fmaxf(rowm_[r_], cv_); \
            colm_[ct_] = fmaxf(colm_[ct_], cv_); \
        } \
    } \
    _Pragma("unroll") for (int r_ = 0; r_ < 4; ++r_) { \
        float v_ = rowm_[r_]; \
        v_ = fmaxf(v_, __shfl_xor(v_, 1, 64)); \
        v_ = fmaxf(v_, __shfl_xor(v_, 2, 64)); \
        v_ = fmaxf(v_, __shfl_xor(v_, 4, 64)); \
        v_ = fmaxf(v_, __shfl_xor(v_, 8, 64)); \
        rowm_[r_] = v_; \
    } \
    if (c == 0) { \
        _Pragma("unroll") for (int r_ = 0; r_ < 4; ++r_) \
            out[(b * SS + m0 + q * 4 + r_) * 160 + dir * 80 + 20 + l0 + (LI)] = rowm_[r_]; \
    } \
    _Pragma("unroll") for (int ct_ = 0; ct_ < 4; ++ct_) { \
        float v_ = colm_[ct_]; \
        v_ = fmaxf(v_, __shfl_xor(v_, 16, 64)); \
        v_ = fmaxf(v_, __shfl_xor(v_, 32, 64)); \
        colm_[ct_] = v_; \
    } \
    if (q == 0) { \
        _Pragma("unroll") for (int ct_ = 0; ct_ < 4; ++ct_) \
            cmL5[(LI) * 256 + wv_ * 64 + ct_ * 16 + c] = colm_[ct_]; \
    } \
} while (0)

        if (wv_ < 4) {
            C_EPI(0, acc0);
            C_EPI(1, acc1);
            C_EPI(2, acc2);
            f32x4 acc3[4] = {z4, z4, z4, z4};
            f32x4 acc4[4] = {z4, z4, z4, z4};
            for (int ks = 0; ks < 7; ++ks) {
                int kb = ks * 32 + q * 8;
                f16x8v ar  = *(const f16x8v*)&ATr[(m0 + c) * KST + kb];
                f16x8v ww3 = *(const f16x8v*)&w2L[3 * KST + kb];
                f16x8v ww4 = *(const f16x8v*)&w2L[4 * KST + kb];
                f16x8v af3 = ar * ww3, af4 = ar * ww4;
#pragma unroll
                for (int ct = 0; ct < 4; ++ct) {
                    f16x8v br = *(const f16x8v*)&BTr[(ct * 16 + c) * KST + kb];
                    acc3[ct] = __builtin_amdgcn_mfma_f32_16x16x32_f16(af3, br, acc3[ct], 0, 0, 0);
                    acc4[ct] = __builtin_amdgcn_mfma_f32_16x16x32_f16(af4, br, acc4[ct], 0, 0, 0);
                }
            }
            C_EPI(3, acc3);
            C_EPI(4, acc4);
        }
        __syncthreads();   // B3

        if (t < 320) {
            int li = t >> 6, j = t & 63;
            const float* cm = &cmL5[li * 256];
            float mm = fmaxf(fmaxf(cm[j], cm[64 + j]), fmaxf(cm[128 + j], cm[192 + j]));
            out[BB * SS * 160 + (b * SS + j) * 160 + dir * 80 + 20 + l0 + li] = mm;
        }
#undef C_EPI
    }
}

extern "C" void kernel_launch(void* const* d_in, const int* in_sizes, int n_in,
                              void* d_out, int out_size, void* d_ws, size_t ws_size,
                              hipStream_t stream) {
    const float* conp = (const float*)d_in[0];
    const float* conh = (const float*)d_in[1];
    const float* w1 = (const float*)d_in[2];
    const float* w2 = (const float*)d_in[3];
    const float* w3 = (const float*)d_in[4];
    const float* w4 = (const float*)d_in[5];
    const float* w5 = (const float*)d_in[6];
    const float* w6 = (const float*)d_in[7];
    const float* w7 = (const float*)d_in[8];
    const float* w8 = (const float*)d_in[9];
    float* out = (float*)d_out;
    (void)d_ws; (void)ws_size;

    fused_all_kernel<<<512, 512, 0, stream>>>(conp, conh,
                                              w1, w2, w3, w4, w5, w6, w7, w8, out);
}

// Round 12
// 99.672 us; speedup vs baseline: 1.0269x; 1.0269x over previous
//
#include <hip/hip_runtime.h>
#include <hip/hip_bf16.h>
#include <math.h>

#define EPS 1e-8f
#define BB 32
#define SS 64
#define HH 200
#define LL 20
#define KST 232   // f16 LDS row stride (464B -> 2-way bank walk)
#define S16ST 72  // S16 row stride (f16)
#define BHST 72   // BH row stride (f16)
#define MLST 208  // meanL row stride (f16)

typedef float f32x4 __attribute__((ext_vector_type(4)));
typedef _Float16 f16x8v __attribute__((ext_vector_type(8)));
typedef _Float16 f16x2 __attribute__((ext_vector_type(2)));

// ONE kernel, grid 768 x 512. r12 = r10 math VERBATIM; only the blockIdx->work
// mapping changes: LJF order — type-C blocks (longest: 2x staging, ~140 MFMA/wave)
// occupy blockIdx [0,256) so all start in residency round 1; the 512 short type-A
// blocks stream into freed slots. XCD-contiguous swizzle inside each segment.
//
// Type A LDS (floats, 19104 = 76.4 KB -> 2 blocks/CU): as r9/r10.
// Type C LDS (floats, 17352): ATr 64xKST f16 | BTr | w2L 5xKST | nA5 | nB5 | cmL5.
__global__ __launch_bounds__(512, 4) void fused_all_kernel(
        const float* __restrict__ conp, const float* __restrict__ conh,
        const float* __restrict__ w1, const float* __restrict__ w2,
        const float* __restrict__ w3, const float* __restrict__ w4,
        const float* __restrict__ w5, const float* __restrict__ w6,
        const float* __restrict__ w7, const float* __restrict__ w8,
        float* __restrict__ out) {
    __shared__ __align__(16) float smem[19104];
    int t = threadIdx.x;

    // LJF dispatch: C first ([0,256), 8x32 XCD-bijective), then A ([256,768), 8x64)
    int rem, grp;
    if (blockIdx.x < 256) {
        rem = 2;
        grp = ((blockIdx.x & 7) * 32) + (blockIdx.x >> 3);
    } else {
        int abid = blockIdx.x - 256;
        int aidx = ((abid & 7) * 64) + (abid >> 3);
        rem = aidx & 1;
        grp = aidx >> 1;
    }

    if (rem < 2) {
        // ================================ type A (16 self-rows, f16) — r10 VERBATIM
        _Float16* AT16 = (_Float16*)smem;
        _Float16* BT16 = (_Float16*)(smem + 1856);
        _Float16* BHh  = (_Float16*)(smem + 9280);
        _Float16* S16h = (_Float16*)(smem + 16768);
        float* nrmA  = smem + 17344;
        float* nrmB  = smem + 17360;
        _Float16* meanLh = (_Float16*)(smem + 17440);
        _Float16* PB = (_Float16*)smem;            // phase 3: 48xKST
        _Float16* WB = (_Float16*)(smem + 5568);   // phase 3: 32xKST

        int blk = grp * 2 + rem;       // 0..511
        int qh = blk & 3;              // 16-row quarter of self side
        int sdb = blk >> 2;
        int b = sdb & 31, sd = sdb >> 5;
        int dir = sd & 1, side = sd >> 1;
        const float* selfb = side ? conh : conp;
        const float* oppb  = side ? conp : conh;
        int fidx = dir ? 0 : (SS - 1);
        const float* fvr = oppb + (b * SS + fidx) * (2 * HH) + dir * HH;

        int arow = t / 25, ack = t % 25;

        float xr[8], yv0[8];
        if (t < 400) {
            const float* xp = selfb + (b * SS + qh * 16 + arow) * (2 * HH) + dir * HH + ack * 8;
            *(float4*)&xr[0] = *(const float4*)xp; *(float4*)&xr[4] = *(const float4*)(xp + 4);
            *(float4*)&yv0[0] = *(const float4*)(fvr + ack * 8);
            *(float4*)&yv0[4] = *(const float4*)(fvr + ack * 8 + 4);
            f16x8v r8;
#pragma unroll
            for (int i = 0; i < 8; ++i) r8[i] = (_Float16)xr[i];
            *(f16x8v*)&AT16[arow * KST + ack * 8] = r8;
        }
        {
            f16x8v z8 = (f16x8v)(_Float16)0.f;
            if (t < 312) {
                if (t < 48) { int row = t / 3, ckp = 25 + t % 3;
                    *(f16x8v*)&AT16[row * KST + ckp * 8] = z8;
                } else if (t < 240) { int e2 = t - 48; int row = e2 / 3, ckp = 25 + e2 % 3;
                    *(f16x8v*)&BT16[row * KST + ckp * 8] = z8;
                } else { int e2 = t - 240; int row = 200 + e2 / 9, c8 = (e2 % 9) * 8;
                    *(f16x8v*)&BHh[row * BHST + c8] = z8;
                }
            }
        }
        for (int e = t; e < 1600; e += 512) {
            int rw = e / 25, ck = e % 25, k = ck * 8;
            const float* xp = oppb + (b * SS + rw) * (2 * HH) + dir * HH + k;
            float xv[8];
            *(float4*)&xv[0] = *(const float4*)xp; *(float4*)&xv[4] = *(const float4*)(xp + 4);
            f16x8v r8;
#pragma unroll
            for (int i = 0; i < 8; ++i) r8[i] = (_Float16)xv[i];
            *(f16x8v*)&BT16[rw * KST + k] = r8;
        }
        __syncthreads();   // B1

        int wv_ = __builtin_amdgcn_readfirstlane(t >> 6);
        int lane = t & 63;
        int q = lane >> 4, c = lane & 15;

        f32x4 accS = (f32x4){0.f, 0.f, 0.f, 0.f};
        if (wv_ < 4) {
            int ct = wv_;
            for (int ks = 0; ks < 7; ++ks) {
                int kb = ks * 32 + q * 8;
                f16x8v af  = *(const f16x8v*)&AT16[c * KST + kb];
                f16x8v bf_ = *(const f16x8v*)&BT16[(ct * 16 + c) * KST + kb];
                accS = __builtin_amdgcn_mfma_f32_16x16x32_f16(af, bf_, accS, 0, 0, 0);
            }
        } else {
            int dt = wv_ - 4;
            f32x4 accB = (f32x4){0.f, 0.f, 0.f, 0.f};
            for (int ks = 0; ks < 7; ++ks) {
                int kb = ks * 32 + q * 8;
                f16x8v bf_ = *(const f16x8v*)&BT16[(dt * 16 + c) * KST + kb];
                accB = __builtin_amdgcn_mfma_f32_16x16x32_f16(bf_, bf_, accB, 0, 0, 0);
            }
            if ((c >> 2) == q) nrmB[dt * 16 + c] = accB[c & 3];
            if (dt == 0) {
                f32x4 accA = (f32x4){0.f, 0.f, 0.f, 0.f};
                for (int ks = 0; ks < 7; ++ks) {
                    int kb = ks * 32 + q * 8;
                    f16x8v af = *(const f16x8v*)&AT16[c * KST + kb];
                    accA = __builtin_amdgcn_mfma_f32_16x16x32_f16(af, af, accA, 0, 0, 0);
                }
                if ((c >> 2) == q) nrmA[c] = accA[c & 3];
            } else {
                for (int ch = dt - 1; ch < 25; ch += 3) {
                    f16x8v v = *(const f16x8v*)&BT16[lane * KST + ch * 8];
#pragma unroll
                    for (int i = 0; i < 8; ++i) BHh[(ch * 8 + i) * BHST + lane] = v[i];
                }
            }
        }
        __syncthreads();   // B2

        if (wv_ < 4) {
            int col = wv_ * 16 + c;
            float no = sqrtf(nrmB[col]);
#pragma unroll
            for (int r = 0; r < 4; ++r) {
                int row = q * 4 + r;
                float ns = sqrtf(nrmA[row]);
                S16h[row * S16ST + col] = (_Float16)(accS[r] / fmaxf(ns * no, EPS));
            }
        }
        __syncthreads();   // B3

        float wf0[8], wf1[8], wf2[8];
        if (t < 500) {
            int wl = t / 25, wck = t % 25;
            const float* wp0 = (dir ? w2 : w1) + wl * HH + wck * 8;
            const float* wp1 = (dir ? w6 : w5) + wl * HH + wck * 8;
            const float* wp2 = (dir ? w8 : w7) + wl * HH + wck * 8;
            *(float4*)&wf0[0] = *(const float4*)wp0; *(float4*)&wf0[4] = *(const float4*)(wp0 + 4);
            *(float4*)&wf1[0] = *(const float4*)wp1; *(float4*)&wf1[4] = *(const float4*)(wp1 + 4);
            *(float4*)&wf2[0] = *(const float4*)wp2; *(float4*)&wf2[4] = *(const float4*)(wp2 + 4);
        }

        f16x2 mx0, mx1, mx2, mx3;
        {
            f16x2 ninf = {(_Float16)(-INFINITY), (_Float16)(-INFINITY)};
            mx0 = ninf; mx1 = ninf; mx2 = ninf; mx3 = ninf;
        }
        if (wv_ == 7) {
            for (int nt = 0; nt < 13; ++nt) {
                f32x4 macc = (f32x4){0.f, 0.f, 0.f, 0.f};
#pragma unroll
                for (int k2 = 0; k2 < 2; ++k2) {
                    int kb = k2 * 32 + q * 8;
                    f16x8v sa = *(const f16x8v*)&S16h[c * S16ST + kb];
                    f16x8v bh = *(const f16x8v*)&BHh[(nt * 16 + c) * BHST + kb];
                    macc = __builtin_amdgcn_mfma_f32_16x16x32_f16(sa, bh, macc, 0, 0, 0);
                }
                int h = nt * 16 + c;
                if (h < 200) {
#pragma unroll
                    for (int r = 0; r < 4; ++r)
                        meanLh[(q * 4 + r) * MLST + h] = (_Float16)(macc[r] * 0.125f);
                }
            }
        } else if (t < 400) {
            const _Float16* srow = &S16h[arow * S16ST];
            const _Float16* bcol = &BT16[ack * 8];
            for (int kg = 0; kg < 8; ++kg) {
                f16x8v sr = *(const f16x8v*)&srow[kg * 8];
#pragma unroll
                for (int kk = 0; kk < 8; ++kk) {
                    _Float16 sh = sr[kk];
                    f16x2 sv = {sh, sh};
                    f16x8v bv = *(const f16x8v*)&bcol[(kg * 8 + kk) * KST];
                    f16x2 p0 = sv * __builtin_shufflevector(bv, bv, 0, 1);
                    f16x2 p1 = sv * __builtin_shufflevector(bv, bv, 2, 3);
                    f16x2 p2 = sv * __builtin_shufflevector(bv, bv, 4, 5);
                    f16x2 p3 = sv * __builtin_shufflevector(bv, bv, 6, 7);
                    mx0 = __builtin_elementwise_max(mx0, p0);
                    mx1 = __builtin_elementwise_max(mx1, p1);
                    mx2 = __builtin_elementwise_max(mx2, p2);
                    mx3 = __builtin_elementwise_max(mx3, p3);
                }
            }
        }
        __syncthreads();   // B4

#pragma unroll
        for (int m = 0; m < 3; ++m) {
            if (t < 400) {
                float yv[8];
                if (m == 0) {
#pragma unroll
                    for (int i = 0; i < 8; ++i) yv[i] = yv0[i];
                } else if (m == 1) {
                    f16x8v yl = *(const f16x8v*)&meanLh[arow * MLST + ack * 8];
#pragma unroll
                    for (int i = 0; i < 8; ++i) yv[i] = (float)yl[i];
                } else {
                    yv[0] = (float)mx0[0]; yv[1] = (float)mx0[1];
                    yv[2] = (float)mx1[0]; yv[3] = (float)mx1[1];
                    yv[4] = (float)mx2[0]; yv[5] = (float)mx2[1];
                    yv[6] = (float)mx3[0]; yv[7] = (float)mx3[1];
                }
                f16x8v r1, r2;
#pragma unroll
                for (int i = 0; i < 8; ++i) {
                    r1[i] = (_Float16)(xr[i] * yv[i]);
                    r2[i] = (_Float16)(yv[i] * yv[i]);
                }
                if (m == 0) {
                    f16x8v r0;
#pragma unroll
                    for (int i = 0; i < 8; ++i) r0[i] = (_Float16)(xr[i] * xr[i]);
                    *(f16x8v*)&PB[(0 * 16 + arow) * KST + ack * 8] = r0;
                }
                *(f16x8v*)&PB[(1 * 16 + arow) * KST + ack * 8] = r1;
                *(f16x8v*)&PB[(2 * 16 + arow) * KST + ack * 8] = r2;
            }
            if (t < 500) {
                int wl = t / 25, wck = t % 25;
                f16x8v wr;
                if (m == 0) {
#pragma unroll
                    for (int i = 0; i < 8; ++i) wr[i] = (_Float16)(wf0[i] * wf0[i]);
                } else if (m == 1) {
#pragma unroll
                    for (int i = 0; i < 8; ++i) wr[i] = (_Float16)(wf1[i] * wf1[i]);
                } else {
#pragma unroll
                    for (int i = 0; i < 8; ++i) wr[i] = (_Float16)(wf2[i] * wf2[i]);
                }
                *(f16x8v*)&WB[wl * KST + wck * 8] = wr;
            }
            if (m == 0) {
                f16x8v z8 = (f16x8v)(_Float16)0.f;
                for (int e = t; e < 540; e += 512) {
                    if (e < 144) { int row = e / 3, ckp = 25 + e % 3;
                        *(f16x8v*)&PB[row * KST + ckp * 8] = z8;
                    } else if (e < 480) { int e2 = e - 144; int row = 20 + e2 / 28, ckp = e2 % 28;
                        *(f16x8v*)&WB[row * KST + ckp * 8] = z8;
                    } else { int e2 = e - 480; int row = e2 / 3, ckp = 25 + e2 % 3;
                        *(f16x8v*)&WB[row * KST + ckp * 8] = z8;
                    }
                }
            }
            __syncthreads();

            if (wv_ < 2) {
                int ntile = wv_;
                f32x4 accA = (f32x4){0.f, 0.f, 0.f, 0.f};
                f32x4 accD = (f32x4){0.f, 0.f, 0.f, 0.f};
                f32x4 accB = (f32x4){0.f, 0.f, 0.f, 0.f};
                for (int ks = 0; ks < 7; ++ks) {
                    int kb = ks * 32 + q * 8;
                    f16x8v bfw = *(const f16x8v*)&WB[(ntile * 16 + c) * KST + kb];
                    f16x8v a0 = *(const f16x8v*)&PB[(0 * 16 + c) * KST + kb];
                    f16x8v a1 = *(const f16x8v*)&PB[(1 * 16 + c) * KST + kb];
                    f16x8v a2 = *(const f16x8v*)&PB[(2 * 16 + c) * KST + kb];
                    accA = __builtin_amdgcn_mfma_f32_16x16x32_f16(a0, bfw, accA, 0, 0, 0);
                    accD = __builtin_amdgcn_mfma_f32_16x16x32_f16(a1, bfw, accD, 0, 0, 0);
                    accB = __builtin_amdgcn_mfma_f32_16x16x32_f16(a2, bfw, accB, 0, 0, 0);
                }
                int l_ = ntile * 16 + c;
                if (l_ < LL) {
                    int chunk = (m == 0) ? 0 : (m == 1) ? 40 : 60;
#pragma unroll
                    for (int r = 0; r < 4; ++r) {
                        int s = qh * 16 + q * 4 + r;
                        float cosv = accD[r] / fmaxf(sqrtf(accA[r] * accB[r]), EPS);
                        out[side * (BB * SS * 160) + (b * SS + s) * 160 + dir * 80 + chunk + l_] = cosv;
                    }
                }
            }
            if (m < 2) __syncthreads();
        }
    } else {
        // ================================ type C: 5-l pairwise, f16, w^2-on-A (r10 VERBATIM)
        _Float16* ATr = (_Float16*)smem;             // 64xKST raw A (f16)
        _Float16* BTr = (_Float16*)(smem + 7424);    // 64xKST raw B (f16)
        _Float16* w2L = (_Float16*)(smem + 14848);   // 5xKST w^2 (f16)
        float* nA5  = smem + 15432;                  // 5x64
        float* nB5  = smem + 15752;                  // 5x64
        float* cmL5 = smem + 16072;                  // 5x256

        int cblk = grp;              // 0..255
        int lg = cblk & 3;
        int db = cblk >> 2;          // 0..63
        int b = db & 31, dir = db >> 5;
        int l0 = lg * 5;
        const float* wsrc = dir ? w4 : w3;
        const float* Ag = conp + dir * HH;
        const float* Bg = conh + dir * HH;

        for (int e = t; e < 3200; e += 512) {
            int half = (e >= 1600) ? 1 : 0;
            int e2 = e - half * 1600;
            int rw = e2 / 25, ck = e2 % 25, k = ck * 8;
            const float* xp = (half ? Bg : Ag) + (b * SS + rw) * (2 * HH) + k;
            float xv[8];
            *(float4*)&xv[0] = *(const float4*)xp; *(float4*)&xv[4] = *(const float4*)(xp + 4);
            f16x8v r8;
#pragma unroll
            for (int i = 0; i < 8; ++i) r8[i] = (_Float16)xv[i];
            _Float16* dst = half ? BTr : ATr;
            *(f16x8v*)&dst[rw * KST + k] = r8;
        }
        {
            f16x8v z8 = (f16x8v)(_Float16)0.f;
            if (t < 384) {
                int half = (t >= 192) ? 1 : 0;
                int e2 = t - half * 192;
                int row = e2 / 3, ckp = 25 + e2 % 3;
                _Float16* dst = half ? BTr : ATr;
                *(f16x8v*)&dst[row * KST + ckp * 8] = z8;
            } else if (t < 399) {
                int e2 = t - 384;
                int wl = e2 / 3, ckp = 25 + e2 % 3;
                *(f16x8v*)&w2L[wl * KST + ckp * 8] = z8;
            }
            if (t < 125) {
                int wl = t / 25, wck = t % 25;
                const float* wp = wsrc + (l0 + wl) * HH + wck * 8;
                float wvv[8];
                *(float4*)&wvv[0] = *(const float4*)wp; *(float4*)&wvv[4] = *(const float4*)(wp + 4);
                f16x8v r8;
#pragma unroll
                for (int i = 0; i < 8; ++i) r8[i] = (_Float16)(wvv[i] * wvv[i]);
                *(f16x8v*)&w2L[wl * KST + wck * 8] = r8;
            }
        }
        __syncthreads();   // B1

        int wv_ = __builtin_amdgcn_readfirstlane(t >> 6);
        int lane = t & 63;
        int q = lane >> 4, c = lane & 15;
        int m0 = (wv_ & 3) * 16;

        f32x4 z4 = (f32x4){0.f, 0.f, 0.f, 0.f};
        f32x4 acc0[4] = {z4, z4, z4, z4};
        f32x4 acc1[4] = {z4, z4, z4, z4};
        f32x4 acc2[4] = {z4, z4, z4, z4};

        if (wv_ < 4) {
            for (int ks = 0; ks < 7; ++ks) {
                int kb = ks * 32 + q * 8;
                f16x8v ar  = *(const f16x8v*)&ATr[(m0 + c) * KST + kb];
                f16x8v ww0 = *(const f16x8v*)&w2L[0 * KST + kb];
                f16x8v ww1 = *(const f16x8v*)&w2L[1 * KST + kb];
                f16x8v ww2 = *(const f16x8v*)&w2L[2 * KST + kb];
                f16x8v af0 = ar * ww0, af1 = ar * ww1, af2 = ar * ww2;
#pragma unroll
                for (int ct = 0; ct < 4; ++ct) {
                    f16x8v br = *(const f16x8v*)&BTr[(ct * 16 + c) * KST + kb];
                    acc0[ct] = __builtin_amdgcn_mfma_f32_16x16x32_f16(af0, br, acc0[ct], 0, 0, 0);
                    acc1[ct] = __builtin_amdgcn_mfma_f32_16x16x32_f16(af1, br, acc1[ct], 0, 0, 0);
                    acc2[ct] = __builtin_amdgcn_mfma_f32_16x16x32_f16(af2, br, acc2[ct], 0, 0, 0);
                }
            }
        } else {
            int d0 = (wv_ - 4) * 16;
            f32x4 nacA[5] = {z4, z4, z4, z4, z4};
            f32x4 nacB[5] = {z4, z4, z4, z4, z4};
            for (int ks = 0; ks < 7; ++ks) {
                int kb = ks * 32 + q * 8;
                f16x8v ar = *(const f16x8v*)&ATr[(d0 + c) * KST + kb];
                f16x8v br = *(const f16x8v*)&BTr[(d0 + c) * KST + kb];
#pragma unroll
                for (int li = 0; li < 5; ++li) {
                    f16x8v wf = *(const f16x8v*)&w2L[li * KST + kb];
                    f16x8v afw = ar * wf;
                    f16x8v bfw = br * wf;
                    nacA[li] = __builtin_amdgcn_mfma_f32_16x16x32_f16(afw, ar, nacA[li], 0, 0, 0);
                    nacB[li] = __builtin_amdgcn_mfma_f32_16x16x32_f16(bfw, br, nacB[li], 0, 0, 0);
                }
            }
            if ((c >> 2) == q) {
#pragma unroll
                for (int li = 0; li < 5; ++li) {
                    nA5[li * 64 + d0 + c] = nacA[li][c & 3];
                    nB5[li * 64 + d0 + c] = nacB[li][c & 3];
                }
            }
        }
        __syncthreads();   // B2

#define C_EPI(LI, ACC) do { \
    float na_[4], nb_[4]; \
    _Pragma("unroll") for (int r_ = 0; r_ < 4; ++r_) na_[r_] = sqrtf(nA5[(LI) * 64 + m0 + q * 4 + r_]); \
    _Pragma("unroll") for (int ct_ = 0; ct_ < 4; ++ct_) nb_[ct_] = sqrtf(nB5[(LI) * 64 + ct_ * 16 + c]); \
    float rowm_[4] = {-INFINITY, -INFINITY, -INFINITY, -INFINITY}; \
    float colm_[4] = {-INFINITY, -INFINITY, -INFINITY, -INFINITY}; \
    _Pragma("unroll") for (int ct_ = 0; ct_ < 4; ++ct_) { \
        _Pragma("unroll") for (int r_ = 0; r_ < 4; ++r_) { \
            float cv_ = (ACC)[ct_][r_] / fmaxf(na_[r_] * nb_[ct_], EPS); \
            rowm_[r_] = fmaxf(rowm_[r_], cv_); \
            colm_[ct_] = fmaxf(colm_[ct_], cv_); \
        } \
    } \
    _Pragma("unroll") for (int r_ = 0; r_ < 4; ++r_) { \
        float v_ = rowm_[r_]; \
        v_ = fmaxf(v_, __shfl_xor(v_, 1, 64)); \
        v_ = fmaxf(v_, __shfl_xor(v_, 2, 64)); \
        v_ = fmaxf(v_, __shfl_xor(v_, 4, 64)); \
        v_ = fmaxf(v_, __shfl_xor(v_, 8, 64)); \
        rowm_[r_] = v_; \
    } \
    if (c == 0) { \
        _Pragma("unroll") for (int r_ = 0; r_ < 4; ++r_) \
            out[(b * SS + m0 + q * 4 + r_) * 160 + dir * 80 + 20 + l0 + (LI)] = rowm_[r_]; \
    } \
    _Pragma("unroll") for (int ct_ = 0; ct_ < 4; ++ct_) { \
        float v_ = colm_[ct_]; \
        v_ = fmaxf(v_, __shfl_xor(v_, 16, 64)); \
        v_ = fmaxf(v_, __shfl_xor(v_, 32, 64)); \
        colm_[ct_] = v_; \
    } \
    if (q == 0) { \
        _Pragma("unroll") for (int ct_ = 0; ct_ < 4; ++ct_) \
            cmL5[(LI) * 256 + wv_ * 64 + ct_ * 16 + c] = colm_[ct_]; \
    } \
} while (0)

        if (wv_ < 4) {
            C_EPI(0, acc0);
            C_EPI(1, acc1);
            C_EPI(2, acc2);
            f32x4 acc3[4] = {z4, z4, z4, z4};
            f32x4 acc4[4] = {z4, z4, z4, z4};
            for (int ks = 0; ks < 7; ++ks) {
                int kb = ks * 32 + q * 8;
                f16x8v ar  = *(const f16x8v*)&ATr[(m0 + c) * KST + kb];
                f16x8v ww3 = *(const f16x8v*)&w2L[3 * KST + kb];
                f16x8v ww4 = *(const f16x8v*)&w2L[4 * KST + kb];
                f16x8v af3 = ar * ww3, af4 = ar * ww4;
#pragma unroll
                for (int ct = 0; ct < 4; ++ct) {
                    f16x8v br = *(const f16x8v*)&BTr[(ct * 16 + c) * KST + kb];
                    acc3[ct] = __builtin_amdgcn_mfma_f32_16x16x32_f16(af3, br, acc3[ct], 0, 0, 0);
                    acc4[ct] = __builtin_amdgcn_mfma_f32_16x16x32_f16(af4, br, acc4[ct], 0, 0, 0);
                }
            }
            C_EPI(3, acc3);
            C_EPI(4, acc4);
        }
        __syncthreads();   // B3

        if (t < 320) {
            int li = t >> 6, j = t & 63;
            const float* cm = &cmL5[li * 256];
            float mm = fmaxf(fmaxf(cm[j], cm[64 + j]), fmaxf(cm[128 + j], cm[192 + j]));
            out[BB * SS * 160 + (b * SS + j) * 160 + dir * 80 + 20 + l0 + li] = mm;
        }
#undef C_EPI
    }
}

extern "C" void kernel_launch(void* const* d_in, const int* in_sizes, int n_in,
                              void* d_out, int out_size, void* d_ws, size_t ws_size,
                              hipStream_t stream) {
    const float* conp = (const float*)d_in[0];
    const float* conh = (const float*)d_in[1];
    const float* w1 = (const float*)d_in[2];
    const float* w2 = (const float*)d_in[3];
    const float* w3 = (const float*)d_in[4];
    const float* w4 = (const float*)d_in[5];
    const float* w5 = (const float*)d_in[6];
    const float* w6 = (const float*)d_in[7];
    const float* w7 = (const float*)d_in[8];
    const float* w8 = (const float*)d_in[9];
    float* out = (float*)d_out;
    (void)d_ws; (void)ws_size;

    fused_all_kernel<<<768, 512, 0, stream>>>(conp, conh,
                                              w1, w2, w3, w4, w5, w6, w7, w8, out);
}

// Round 13
// 98.997 us; speedup vs baseline: 1.0339x; 1.0068x over previous
//
#include <hip/hip_runtime.h>
#include <hip/hip_bf16.h>
#include <math.h>

#define EPS 1e-8f
#define BB 32
#define SS 64
#define HH 200
#define LL 20
#define KST 232   // f16 LDS row stride (464B -> 2-way bank walk)
#define S16ST 72  // S16 row stride (f16)
#define BHST 72   // BH row stride (f16)
#define MLST 208  // meanL row stride (f16)

typedef float f32x4 __attribute__((ext_vector_type(4)));
typedef _Float16 f16x8v __attribute__((ext_vector_type(8)));
typedef _Float16 f16x2 __attribute__((ext_vector_type(2)));

// ONE kernel, grid 768 x 512. r13 = r12 (LJF dispatch, type-C verbatim) with
// type-A phase 3 DOUBLE-BUFFERED: PB/WB buf0 in the AT/BT zone, buf1 in the
// dead BH/S16/nrm zone; stage(m+1) overlaps MFMA(m); 3 barriers instead of 5.
// x^2 (PB set 0) is re-staged per m (was persistent) — same value, bit-identical.
//
// Type A LDS (floats, 20224 = 80.9 KB -> still 2 blocks/CU):
//   phases 1-2: AT16 [0,1856) | BT16 [1856,9280) | BH [9280,16768) |
//               S16 [16768,17344) | nrmA/nrmB [17344,17424) | meanL [18560,20224)
//   phase 3:    PB0 [0,5568) WB0 [5568,9280) | PB1 [9280,14848) WB1 [14848,18560)
//               (meanL survives at [18560,20224))
// Type C LDS: r10/r12 verbatim (17352 fl).
__global__ __launch_bounds__(512, 4) void fused_all_kernel(
        const float* __restrict__ conp, const float* __restrict__ conh,
        const float* __restrict__ w1, const float* __restrict__ w2,
        const float* __restrict__ w3, const float* __restrict__ w4,
        const float* __restrict__ w5, const float* __restrict__ w6,
        const float* __restrict__ w7, const float* __restrict__ w8,
        float* __restrict__ out) {
    __shared__ __align__(16) float smem[20224];
    int t = threadIdx.x;

    // LJF dispatch: C first ([0,256), 8x32 XCD-bijective), then A ([256,768), 8x64)
    int rem, grp;
    if (blockIdx.x < 256) {
        rem = 2;
        grp = ((blockIdx.x & 7) * 32) + (blockIdx.x >> 3);
    } else {
        int abid = blockIdx.x - 256;
        int aidx = ((abid & 7) * 64) + (abid >> 3);
        rem = aidx & 1;
        grp = aidx >> 1;
    }

    if (rem < 2) {
        // ================================ type A (16 self-rows, f16)
        _Float16* AT16 = (_Float16*)smem;
        _Float16* BT16 = (_Float16*)(smem + 1856);
        _Float16* BHh  = (_Float16*)(smem + 9280);
        _Float16* S16h = (_Float16*)(smem + 16768);
        float* nrmA  = smem + 17344;
        float* nrmB  = smem + 17360;
        _Float16* meanLh = (_Float16*)(smem + 18560);
        _Float16* PB0 = (_Float16*)smem;             // phase 3 buf0
        _Float16* WB0 = (_Float16*)(smem + 5568);
        _Float16* PB1 = (_Float16*)(smem + 9280);    // phase 3 buf1
        _Float16* WB1 = (_Float16*)(smem + 14848);

        int blk = grp * 2 + rem;       // 0..511
        int qh = blk & 3;              // 16-row quarter of self side
        int sdb = blk >> 2;
        int b = sdb & 31, sd = sdb >> 5;
        int dir = sd & 1, side = sd >> 1;
        const float* selfb = side ? conh : conp;
        const float* oppb  = side ? conp : conh;
        int fidx = dir ? 0 : (SS - 1);
        const float* fvr = oppb + (b * SS + fidx) * (2 * HH) + dir * HH;

        int arow = t / 25, ack = t % 25;

        float xr[8], yv0[8];
        if (t < 400) {
            const float* xp = selfb + (b * SS + qh * 16 + arow) * (2 * HH) + dir * HH + ack * 8;
            *(float4*)&xr[0] = *(const float4*)xp; *(float4*)&xr[4] = *(const float4*)(xp + 4);
            *(float4*)&yv0[0] = *(const float4*)(fvr + ack * 8);
            *(float4*)&yv0[4] = *(const float4*)(fvr + ack * 8 + 4);
            f16x8v r8;
#pragma unroll
            for (int i = 0; i < 8; ++i) r8[i] = (_Float16)xr[i];
            *(f16x8v*)&AT16[arow * KST + ack * 8] = r8;
        }
        {
            f16x8v z8 = (f16x8v)(_Float16)0.f;
            if (t < 312) {
                if (t < 48) { int row = t / 3, ckp = 25 + t % 3;
                    *(f16x8v*)&AT16[row * KST + ckp * 8] = z8;
                } else if (t < 240) { int e2 = t - 48; int row = e2 / 3, ckp = 25 + e2 % 3;
                    *(f16x8v*)&BT16[row * KST + ckp * 8] = z8;
                } else { int e2 = t - 240; int row = 200 + e2 / 9, c8 = (e2 % 9) * 8;
                    *(f16x8v*)&BHh[row * BHST + c8] = z8;
                }
            }
        }
        for (int e = t; e < 1600; e += 512) {
            int rw = e / 25, ck = e % 25, k = ck * 8;
            const float* xp = oppb + (b * SS + rw) * (2 * HH) + dir * HH + k;
            float xv[8];
            *(float4*)&xv[0] = *(const float4*)xp; *(float4*)&xv[4] = *(const float4*)(xp + 4);
            f16x8v r8;
#pragma unroll
            for (int i = 0; i < 8; ++i) r8[i] = (_Float16)xv[i];
            *(f16x8v*)&BT16[rw * KST + k] = r8;
        }
        __syncthreads();   // B1

        int wv_ = __builtin_amdgcn_readfirstlane(t >> 6);
        int lane = t & 63;
        int q = lane >> 4, c = lane & 15;

        f32x4 accS = (f32x4){0.f, 0.f, 0.f, 0.f};
        if (wv_ < 4) {
            int ct = wv_;
            for (int ks = 0; ks < 7; ++ks) {
                int kb = ks * 32 + q * 8;
                f16x8v af  = *(const f16x8v*)&AT16[c * KST + kb];
                f16x8v bf_ = *(const f16x8v*)&BT16[(ct * 16 + c) * KST + kb];
                accS = __builtin_amdgcn_mfma_f32_16x16x32_f16(af, bf_, accS, 0, 0, 0);
            }
        } else {
            int dt = wv_ - 4;
            f32x4 accB = (f32x4){0.f, 0.f, 0.f, 0.f};
            for (int ks = 0; ks < 7; ++ks) {
                int kb = ks * 32 + q * 8;
                f16x8v bf_ = *(const f16x8v*)&BT16[(dt * 16 + c) * KST + kb];
                accB = __builtin_amdgcn_mfma_f32_16x16x32_f16(bf_, bf_, accB, 0, 0, 0);
            }
            if ((c >> 2) == q) nrmB[dt * 16 + c] = accB[c & 3];
            if (dt == 0) {
                f32x4 accA = (f32x4){0.f, 0.f, 0.f, 0.f};
                for (int ks = 0; ks < 7; ++ks) {
                    int kb = ks * 32 + q * 8;
                    f16x8v af = *(const f16x8v*)&AT16[c * KST + kb];
                    accA = __builtin_amdgcn_mfma_f32_16x16x32_f16(af, af, accA, 0, 0, 0);
                }
                if ((c >> 2) == q) nrmA[c] = accA[c & 3];
            } else {
                for (int ch = dt - 1; ch < 25; ch += 3) {
                    f16x8v v = *(const f16x8v*)&BT16[lane * KST + ch * 8];
#pragma unroll
                    for (int i = 0; i < 8; ++i) BHh[(ch * 8 + i) * BHST + lane] = v[i];
                }
            }
        }
        __syncthreads();   // B2

        if (wv_ < 4) {
            int col = wv_ * 16 + c;
            float no = sqrtf(nrmB[col]);
#pragma unroll
            for (int r = 0; r < 4; ++r) {
                int row = q * 4 + r;
                float ns = sqrtf(nrmA[row]);
                S16h[row * S16ST + col] = (_Float16)(accS[r] / fmaxf(ns * no, EPS));
            }
        }
        __syncthreads();   // B3

        float wf0[8], wf1[8], wf2[8];
        if (t < 500) {
            int wl = t / 25, wck = t % 25;
            const float* wp0 = (dir ? w2 : w1) + wl * HH + wck * 8;
            const float* wp1 = (dir ? w6 : w5) + wl * HH + wck * 8;
            const float* wp2 = (dir ? w8 : w7) + wl * HH + wck * 8;
            *(float4*)&wf0[0] = *(const float4*)wp0; *(float4*)&wf0[4] = *(const float4*)(wp0 + 4);
            *(float4*)&wf1[0] = *(const float4*)wp1; *(float4*)&wf1[4] = *(const float4*)(wp1 + 4);
            *(float4*)&wf2[0] = *(const float4*)wp2; *(float4*)&wf2[4] = *(const float4*)(wp2 + 4);
        }

        f16x2 mx0, mx1, mx2, mx3;
        {
            f16x2 ninf = {(_Float16)(-INFINITY), (_Float16)(-INFINITY)};
            mx0 = ninf; mx1 = ninf; mx2 = ninf; mx3 = ninf;
        }
        if (wv_ == 7) {
            for (int nt = 0; nt < 13; ++nt) {
                f32x4 macc = (f32x4){0.f, 0.f, 0.f, 0.f};
#pragma unroll
                for (int k2 = 0; k2 < 2; ++k2) {
                    int kb = k2 * 32 + q * 8;
                    f16x8v sa = *(const f16x8v*)&S16h[c * S16ST + kb];
                    f16x8v bh = *(const f16x8v*)&BHh[(nt * 16 + c) * BHST + kb];
                    macc = __builtin_amdgcn_mfma_f32_16x16x32_f16(sa, bh, macc, 0, 0, 0);
                }
                int h = nt * 16 + c;
                if (h < 200) {
#pragma unroll
                    for (int r = 0; r < 4; ++r)
                        meanLh[(q * 4 + r) * MLST + h] = (_Float16)(macc[r] * 0.125f);
                }
            }
        } else if (t < 400) {
            const _Float16* srow = &S16h[arow * S16ST];
            const _Float16* bcol = &BT16[ack * 8];
            for (int kg = 0; kg < 8; ++kg) {
                f16x8v sr = *(const f16x8v*)&srow[kg * 8];
#pragma unroll
                for (int kk = 0; kk < 8; ++kk) {
                    _Float16 sh = sr[kk];
                    f16x2 sv = {sh, sh};
                    f16x8v bv = *(const f16x8v*)&bcol[(kg * 8 + kk) * KST];
                    f16x2 p0 = sv * __builtin_shufflevector(bv, bv, 0, 1);
                    f16x2 p1 = sv * __builtin_shufflevector(bv, bv, 2, 3);
                    f16x2 p2 = sv * __builtin_shufflevector(bv, bv, 4, 5);
                    f16x2 p3 = sv * __builtin_shufflevector(bv, bv, 6, 7);
                    mx0 = __builtin_elementwise_max(mx0, p0);
                    mx1 = __builtin_elementwise_max(mx1, p1);
                    mx2 = __builtin_elementwise_max(mx2, p2);
                    mx3 = __builtin_elementwise_max(mx3, p3);
                }
            }
        }
        __syncthreads();   // B4 — BT16/BH/S16/nrm all dead; phase-3 overlays may begin

        // ---- phase 3: double-buffered. stage(m) writes x^2, x*y_m, y_m^2 + w_m^2.
#define STAGE_M(MM, PBd, WBd) do { \
    if (t < 400) { \
        float yv[8]; \
        if ((MM) == 0) { \
            _Pragma("unroll") for (int i = 0; i < 8; ++i) yv[i] = yv0[i]; \
        } else if ((MM) == 1) { \
            f16x8v yl = *(const f16x8v*)&meanLh[arow * MLST + ack * 8]; \
            _Pragma("unroll") for (int i = 0; i < 8; ++i) yv[i] = (float)yl[i]; \
        } else { \
            yv[0] = (float)mx0[0]; yv[1] = (float)mx0[1]; \
            yv[2] = (float)mx1[0]; yv[3] = (float)mx1[1]; \
            yv[4] = (float)mx2[0]; yv[5] = (float)mx2[1]; \
            yv[6] = (float)mx3[0]; yv[7] = (float)mx3[1]; \
        } \
        f16x8v r0, r1, r2; \
        _Pragma("unroll") for (int i = 0; i < 8; ++i) { \
            r0[i] = (_Float16)(xr[i] * xr[i]); \
            r1[i] = (_Float16)(xr[i] * yv[i]); \
            r2[i] = (_Float16)(yv[i] * yv[i]); \
        } \
        *(f16x8v*)&(PBd)[(0 * 16 + arow) * KST + ack * 8] = r0; \
        *(f16x8v*)&(PBd)[(1 * 16 + arow) * KST + ack * 8] = r1; \
        *(f16x8v*)&(PBd)[(2 * 16 + arow) * KST + ack * 8] = r2; \
    } \
    if (t < 500) { \
        int wl_ = t / 25, wck_ = t % 25; \
        f16x8v wr; \
        if ((MM) == 0) { _Pragma("unroll") for (int i = 0; i < 8; ++i) wr[i] = (_Float16)(wf0[i] * wf0[i]); } \
        else if ((MM) == 1) { _Pragma("unroll") for (int i = 0; i < 8; ++i) wr[i] = (_Float16)(wf1[i] * wf1[i]); } \
        else { _Pragma("unroll") for (int i = 0; i < 8; ++i) wr[i] = (_Float16)(wf2[i] * wf2[i]); } \
        *(f16x8v*)&(WBd)[wl_ * KST + wck_ * 8] = wr; \
    } \
} while (0)

#define MFMA_M(MM, PBd, WBd) do { \
    if (wv_ < 2) { \
        int ntile = wv_; \
        f32x4 accA = (f32x4){0.f, 0.f, 0.f, 0.f}; \
        f32x4 accD = (f32x4){0.f, 0.f, 0.f, 0.f}; \
        f32x4 accB = (f32x4){0.f, 0.f, 0.f, 0.f}; \
        for (int ks = 0; ks < 7; ++ks) { \
            int kb = ks * 32 + q * 8; \
            f16x8v bfw = *(const f16x8v*)&(WBd)[(ntile * 16 + c) * KST + kb]; \
            f16x8v a0 = *(const f16x8v*)&(PBd)[(0 * 16 + c) * KST + kb]; \
            f16x8v a1 = *(const f16x8v*)&(PBd)[(1 * 16 + c) * KST + kb]; \
            f16x8v a2 = *(const f16x8v*)&(PBd)[(2 * 16 + c) * KST + kb]; \
            accA = __builtin_amdgcn_mfma_f32_16x16x32_f16(a0, bfw, accA, 0, 0, 0); \
            accD = __builtin_amdgcn_mfma_f32_16x16x32_f16(a1, bfw, accD, 0, 0, 0); \
            accB = __builtin_amdgcn_mfma_f32_16x16x32_f16(a2, bfw, accB, 0, 0, 0); \
        } \
        int l_ = ntile * 16 + c; \
        if (l_ < LL) { \
            int chunk = ((MM) == 0) ? 0 : ((MM) == 1) ? 40 : 60; \
            _Pragma("unroll") for (int r = 0; r < 4; ++r) { \
                int s = qh * 16 + q * 4 + r; \
                float cosv = accD[r] / fmaxf(sqrtf(accA[r] * accB[r]), EPS); \
                out[side * (BB * SS * 160) + (b * SS + s) * 160 + dir * 80 + chunk + l_] = cosv; \
            } \
        } \
    } \
} while (0)

        // stage m=0 into buf0 + one-time pad zeros for BOTH buffers
        STAGE_M(0, PB0, WB0);
        {
            f16x8v z8 = (f16x8v)(_Float16)0.f;
            for (int e = t; e < 1080; e += 512) {
                int bsel = (e >= 540);
                int e2 = e - bsel * 540;
                _Float16* PBd = bsel ? PB1 : PB0;
                _Float16* WBd = bsel ? WB1 : WB0;
                if (e2 < 144) { int row = e2 / 3, ckp = 25 + e2 % 3;
                    *(f16x8v*)&PBd[row * KST + ckp * 8] = z8;
                } else if (e2 < 480) { int e3 = e2 - 144; int row = 20 + e3 / 28, ckp = e3 % 28;
                    *(f16x8v*)&WBd[row * KST + ckp * 8] = z8;
                } else { int e3 = e2 - 480; int row = e3 / 3, ckp = 25 + e3 % 3;
                    *(f16x8v*)&WBd[row * KST + ckp * 8] = z8;
                }
            }
        }
        __syncthreads();   // S1 — buf0 ready

        // m=0: MFMA(buf0) by waves 0-1; stage m=1 into buf1 (disjoint) by all
        MFMA_M(0, PB0, WB0);
        STAGE_M(1, PB1, WB1);
        __syncthreads();   // buf1 ready; buf0 reads drained

        // m=1: MFMA(buf1); stage m=2 into buf0
        MFMA_M(1, PB1, WB1);
        STAGE_M(2, PB0, WB0);
        __syncthreads();   // buf0 ready; buf1 reads drained

        // m=2: MFMA(buf0); block done
        MFMA_M(2, PB0, WB0);
#undef STAGE_M
#undef MFMA_M
    } else {
        // ================================ type C: 5-l pairwise, f16, w^2-on-A (r10/r12 VERBATIM)
        _Float16* ATr = (_Float16*)smem;             // 64xKST raw A (f16)
        _Float16* BTr = (_Float16*)(smem + 7424);    // 64xKST raw B (f16)
        _Float16* w2L = (_Float16*)(smem + 14848);   // 5xKST w^2 (f16)
        float* nA5  = smem + 15432;                  // 5x64
        float* nB5  = smem + 15752;                  // 5x64
        float* cmL5 = smem + 16072;                  // 5x256

        int cblk = grp;              // 0..255
        int lg = cblk & 3;
        int db = cblk >> 2;          // 0..63
        int b = db & 31, dir = db >> 5;
        int l0 = lg * 5;
        const float* wsrc = dir ? w4 : w3;
        const float* Ag = conp + dir * HH;
        const float* Bg = conh + dir * HH;

        for (int e = t; e < 3200; e += 512) {
            int half = (e >= 1600) ? 1 : 0;
            int e2 = e - half * 1600;
            int rw = e2 / 25, ck = e2 % 25, k = ck * 8;
            const float* xp = (half ? Bg : Ag) + (b * SS + rw) * (2 * HH) + k;
            float xv[8];
            *(float4*)&xv[0] = *(const float4*)xp; *(float4*)&xv[4] = *(const float4*)(xp + 4);
            f16x8v r8;
#pragma unroll
            for (int i = 0; i < 8; ++i) r8[i] = (_Float16)xv[i];
            _Float16* dst = half ? BTr : ATr;
            *(f16x8v*)&dst[rw * KST + k] = r8;
        }
        {
            f16x8v z8 = (f16x8v)(_Float16)0.f;
            if (t < 384) {
                int half = (t >= 192) ? 1 : 0;
                int e2 = t - half * 192;
                int row = e2 / 3, ckp = 25 + e2 % 3;
                _Float16* dst = half ? BTr : ATr;
                *(f16x8v*)&dst[row * KST + ckp * 8] = z8;
            } else if (t < 399) {
                int e2 = t - 384;
                int wl = e2 / 3, ckp = 25 + e2 % 3;
                *(f16x8v*)&w2L[wl * KST + ckp * 8] = z8;
            }
            if (t < 125) {
                int wl = t / 25, wck = t % 25;
                const float* wp = wsrc + (l0 + wl) * HH + wck * 8;
                float wvv[8];
                *(float4*)&wvv[0] = *(const float4*)wp; *(float4*)&wvv[4] = *(const float4*)(wp + 4);
                f16x8v r8;
#pragma unroll
                for (int i = 0; i < 8; ++i) r8[i] = (_Float16)(wvv[i] * wvv[i]);
                *(f16x8v*)&w2L[wl * KST + wck * 8] = r8;
            }
        }
        __syncthreads();   // B1

        int wv_ = __builtin_amdgcn_readfirstlane(t >> 6);
        int lane = t & 63;
        int q = lane >> 4, c = lane & 15;
        int m0 = (wv_ & 3) * 16;

        f32x4 z4 = (f32x4){0.f, 0.f, 0.f, 0.f};
        f32x4 acc0[4] = {z4, z4, z4, z4};
        f32x4 acc1[4] = {z4, z4, z4, z4};
        f32x4 acc2[4] = {z4, z4, z4, z4};

        if (wv_ < 4) {
            for (int ks = 0; ks < 7; ++ks) {
                int kb = ks * 32 + q * 8;
                f16x8v ar  = *(const f16x8v*)&ATr[(m0 + c) * KST + kb];
                f16x8v ww0 = *(const f16x8v*)&w2L[0 * KST + kb];
                f16x8v ww1 = *(const f16x8v*)&w2L[1 * KST + kb];
                f16x8v ww2 = *(const f16x8v*)&w2L[2 * KST + kb];
                f16x8v af0 = ar * ww0, af1 = ar * ww1, af2 = ar * ww2;
#pragma unroll
                for (int ct = 0; ct < 4; ++ct) {
                    f16x8v br = *(const f16x8v*)&BTr[(ct * 16 + c) * KST + kb];
                    acc0[ct] = __builtin_amdgcn_mfma_f32_16x16x32_f16(af0, br, acc0[ct], 0, 0, 0);
                    acc1[ct] = __builtin_amdgcn_mfma_f32_16x16x32_f16(af1, br, acc1[ct], 0, 0, 0);
                    acc2[ct] = __builtin_amdgcn_mfma_f32_16x16x32_f16(af2, br, acc2[ct], 0, 0, 0);
                }
            }
        } else {
            int d0 = (wv_ - 4) * 16;
            f32x4 nacA[5] = {z4, z4, z4, z4, z4};
            f32x4 nacB[5] = {z4, z4, z4, z4, z4};
            for (int ks = 0; ks < 7; ++ks) {
                int kb = ks * 32 + q * 8;
                f16x8v ar = *(const f16x8v*)&ATr[(d0 + c) * KST + kb];
                f16x8v br = *(const f16x8v*)&BTr[(d0 + c) * KST + kb];
#pragma unroll
                for (int li = 0; li < 5; ++li) {
                    f16x8v wf = *(const f16x8v*)&w2L[li * KST + kb];
                    f16x8v afw = ar * wf;
                    f16x8v bfw = br * wf;
                    nacA[li] = __builtin_amdgcn_mfma_f32_16x16x32_f16(afw, ar, nacA[li], 0, 0, 0);
                    nacB[li] = __builtin_amdgcn_mfma_f32_16x16x32_f16(bfw, br, nacB[li], 0, 0, 0);
                }
            }
            if ((c >> 2) == q) {
#pragma unroll
                for (int li = 0; li < 5; ++li) {
                    nA5[li * 64 + d0 + c] = nacA[li][c & 3];
                    nB5[li * 64 + d0 + c] = nacB[li][c & 3];
                }
            }
        }
        __syncthreads();   // B2

#define C_EPI(LI, ACC) do { \
    float na_[4], nb_[4]; \
    _Pragma("unroll") for (int r_ = 0; r_ < 4; ++r_) na_[r_] = sqrtf(nA5[(LI) * 64 + m0 + q * 4 + r_]); \
    _Pragma("unroll") for (int ct_ = 0; ct_ < 4; ++ct_) nb_[ct_] = sqrtf(nB5[(LI) * 64 + ct_ * 16 + c]); \
    float rowm_[4] = {-INFINITY, -INFINITY, -INFINITY, -INFINITY}; \
    float colm_[4] = {-INFINITY, -INFINITY, -INFINITY, -INFINITY}; \
    _Pragma("unroll") for (int ct_ = 0; ct_ < 4; ++ct_) { \
        _Pragma("unroll") for (int r_ = 0; r_ < 4; ++r_) { \
            float cv_ = (ACC)[ct_][r_] / fmaxf(na_[r_] * nb_[ct_], EPS); \
            rowm_[r_] = fmaxf(rowm_[r_], cv_); \
            colm_[ct_] = fmaxf(colm_[ct_], cv_); \
        } \
    } \
    _Pragma("unroll") for (int r_ = 0; r_ < 4; ++r_) { \
        float v_ = rowm_[r_]; \
        v_ = fmaxf(v_, __shfl_xor(v_, 1, 64)); \
        v_ = fmaxf(v_, __shfl_xor(v_, 2, 64)); \
        v_ = fmaxf(v_, __shfl_xor(v_, 4, 64)); \
        v_ = fmaxf(v_, __shfl_xor(v_, 8, 64)); \
        rowm_[r_] = v_; \
    } \
    if (c == 0) { \
        _Pragma("unroll") for (int r_ = 0; r_ < 4; ++r_) \
            out[(b * SS + m0 + q * 4 + r_) * 160 + dir * 80 + 20 + l0 + (LI)] = rowm_[r_]; \
    } \
    _Pragma("unroll") for (int ct_ = 0; ct_ < 4; ++ct_) { \
        float v_ = colm_[ct_]; \
        v_ = fmaxf(v_, __shfl_xor(v_, 16, 64)); \
        v_ = fmaxf(v_, __shfl_xor(v_, 32, 64)); \
        colm_[ct_] = v_; \
    } \
    if (q == 0) { \
        _Pragma("unroll") for (int ct_ = 0; ct_ < 4; ++ct_) \
            cmL5[(LI) * 256 + wv_ * 64 + ct_ * 16 + c] = colm_[ct_]; \
    } \
} while (0)

        if (wv_ < 4) {
            C_EPI(0, acc0);
            C_EPI(1, acc1);
            C_EPI(2, acc2);
            f32x4 acc3[4] = {z4, z4, z4, z4};
            f32x4 acc4[4] = {z4, z4, z4, z4};
            for (int ks = 0; ks < 7; ++ks) {
                int kb = ks * 32 + q * 8;
                f16x8v ar  = *(const f16x8v*)&ATr[(m0 + c) * KST + kb];
                f16x8v ww3 = *(const f16x8v*)&w2L[3 * KST + kb];
                f16x8v ww4 = *(const f16x8v*)&w2L[4 * KST + kb];
                f16x8v af3 = ar * ww3, af4 = ar * ww4;
#pragma unroll
                for (int ct = 0; ct < 4; ++ct) {
                    f16x8v br = *(const f16x8v*)&BTr[(ct * 16 + c) * KST + kb];
                    acc3[ct] = __builtin_amdgcn_mfma_f32_16x16x32_f16(af3, br, acc3[ct], 0, 0, 0);
                    acc4[ct] = __builtin_amdgcn_mfma_f32_16x16x32_f16(af4, br, acc4[ct], 0, 0, 0);
                }
            }
            C_EPI(3, acc3);
            C_EPI(4, acc4);
        }
        __syncthreads();   // B3

        if (t < 320) {
            int li = t >> 6, j = t & 63;
            const float* cm = &cmL5[li * 256];
            float mm = fmaxf(fmaxf(cm[j], cm[64 + j]), fmaxf(cm[128 + j], cm[192 + j]));
            out[BB * SS * 160 + (b * SS + j) * 160 + dir * 80 + 20 + l0 + li] = mm;
        }
#undef C_EPI
    }
}

extern "C" void kernel_launch(void* const* d_in, const int* in_sizes, int n_in,
                              void* d_out, int out_size, void* d_ws, size_t ws_size,
                              hipStream_t stream) {
    const float* conp = (const float*)d_in[0];
    const float* conh = (const float*)d_in[1];
    const float* w1 = (const float*)d_in[2];
    const float* w2 = (const float*)d_in[3];
    const float* w3 = (const float*)d_in[4];
    const float* w4 = (const float*)d_in[5];
    const float* w5 = (const float*)d_in[6];
    const float* w6 = (const float*)d_in[7];
    const float* w7 = (const float*)d_in[8];
    const float* w8 = (const float*)d_in[9];
    float* out = (float*)d_out;
    (void)d_ws; (void)ws_size;

    fused_all_kernel<<<768, 512, 0, stream>>>(conp, conh,
                                              w1, w2, w3, w4, w5, w6, w7, w8, out);
}